// Round 6
// baseline (80.723 us; speedup 1.0000x reference)
//
#include <hip/hip_runtime.h>
#include <hip/hip_cooperative_groups.h>
#include <hip/hip_fp16.h>
#include <cmath>

namespace cg = cooperative_groups;

#define NB 32
#define CH 384
#define IH 64
#define IW 64
#define OH 32
#define OW 32
#define PR 70            // padded rows: iy -3..66 -> pr 0..69
#define PW 36            // half-width entries (cols 0..34 used)
#define PLANES (NB * CH) // 12288

// ===========================================================================
// Fused cooperative kernel (templated on grid size; PPB = PLANES/GRID).
// Phase 1: per plane — stage to LDS (parity-split), 7x7+3x3 stride-2 conv,
//          keep outputs packed half2 in registers, atomic fp32 channel stats.
// threadfence + grid.sync()
// Phase 2: per plane — device-scope atomic-load finalized stats, fold BN,
//          unpack register state, affine+add+exact GELU, store.
// ===========================================================================
template <int GRID>
__global__ __launch_bounds__(256, (GRID / 256)) void fused_kernel(
    const float* __restrict__ x,
    const float* __restrict__ w_lk,
    const float* __restrict__ w_sk,
    const float* __restrict__ gamma_lk, const float* __restrict__ beta_lk,
    const float* __restrict__ gamma_sk, const float* __restrict__ beta_sk,
    float* __restrict__ stats,   // [CH][4], zeroed by host memsetAsync
    float* __restrict__ out)
{
    constexpr int PPB = PLANES / GRID;

    __shared__ float sx2[2][PR][PW];
    __shared__ float sred[4 * 4];

    const int tid  = threadIdx.x;
    const int lane = tid & 63;
    const int ox   = tid & 31;
    const int oyq  = tid >> 5;      // 0..7
    const int pr0  = oyq * 8;

    float* sflat = &sx2[0][0][0];
    for (int i = tid; i < 2 * PR * PW; i += 256) sflat[i] = 0.0f;

    unsigned int state[PPB][4];     // packed half2 {y_lk, y_sk} per output px

#pragma unroll
    for (int p = 0; p < PPB; ++p) {
        const int nc = blockIdx.x + p * GRID;
        const int c  = nc % CH;

        __syncthreads();            // prev plane's reads / initial zero done

        const float4* xp4 = (const float4*)(x + (size_t)nc * (IH * IW));
#pragma unroll
        for (int it = 0; it < 4; ++it) {
            const int i = tid + it * 256;
            const float4 v = xp4[i];
            const int r = (i >> 4) + 3;
            const int q = i & 15;
            sx2[1][r][2 * q + 1] = v.x;   // cp = 4q+3 (odd)
            sx2[0][r][2 * q + 2] = v.y;   // cp = 4q+4 (even)
            sx2[1][r][2 * q + 2] = v.z;   // cp = 4q+5 (odd)
            sx2[0][r][2 * q + 3] = v.w;   // cp = 4q+6 (even)
        }
        __syncthreads();

        float wl[49], ws9[9];
#pragma unroll
        for (int t = 0; t < 49; ++t) wl[t] = w_lk[c * 49 + t];
#pragma unroll
        for (int t = 0; t < 9; ++t)  ws9[t] = w_sk[c * 9 + t];

        float accl[4] = {0.f, 0.f, 0.f, 0.f};
        float accs[4] = {0.f, 0.f, 0.f, 0.f};

#pragma unroll
        for (int k = 0; k < 13; ++k) {
            const float e0 = sx2[0][pr0 + k][ox];
            const float o0 = sx2[1][pr0 + k][ox];
            const float e1 = sx2[0][pr0 + k][ox + 1];
            const float o1 = sx2[1][pr0 + k][ox + 1];
            const float e2 = sx2[0][pr0 + k][ox + 2];
            const float o2 = sx2[1][pr0 + k][ox + 2];
            const float e3 = sx2[0][pr0 + k][ox + 3];
#pragma unroll
            for (int j = 0; j < 4; ++j) {
                if (k >= 2 * j && k <= 2 * j + 6) {     // folds at compile time
                    const int ky = k - 2 * j;
                    accl[j] = fmaf(e0, wl[ky * 7 + 0], accl[j]);
                    accl[j] = fmaf(o0, wl[ky * 7 + 1], accl[j]);
                    accl[j] = fmaf(e1, wl[ky * 7 + 2], accl[j]);
                    accl[j] = fmaf(o1, wl[ky * 7 + 3], accl[j]);
                    accl[j] = fmaf(e2, wl[ky * 7 + 4], accl[j]);
                    accl[j] = fmaf(o2, wl[ky * 7 + 5], accl[j]);
                    accl[j] = fmaf(e3, wl[ky * 7 + 6], accl[j]);
                }
                if (k >= 2 * j + 2 && k <= 2 * j + 4) {
                    const int ky = k - 2 * j - 2;
                    accs[j] = fmaf(e1, ws9[ky * 3 + 0], accs[j]);
                    accs[j] = fmaf(o1, ws9[ky * 3 + 1], accs[j]);
                    accs[j] = fmaf(e2, ws9[ky * 3 + 2], accs[j]);
                }
            }
        }

        float s0 = 0.f, s1 = 0.f, s2 = 0.f, s3 = 0.f;
#pragma unroll
        for (int j = 0; j < 4; ++j) {
            const __half2 h = __floats2half2_rn(accl[j], accs[j]);
            state[p][j] = *reinterpret_cast<const unsigned int*>(&h);
            s0 += accl[j]; s1 += accl[j] * accl[j];
            s2 += accs[j]; s3 += accs[j] * accs[j];
        }

#pragma unroll
        for (int off = 32; off >= 1; off >>= 1) {
            s0 += __shfl_down(s0, off);
            s1 += __shfl_down(s1, off);
            s2 += __shfl_down(s2, off);
            s3 += __shfl_down(s3, off);
        }
        const int wave = tid >> 6;
        if (lane == 0) {
            sred[wave * 4 + 0] = s0; sred[wave * 4 + 1] = s1;
            sred[wave * 4 + 2] = s2; sred[wave * 4 + 3] = s3;
        }
        __syncthreads();
        if (tid == 0) {
            float t0 = 0.f, t1 = 0.f, t2 = 0.f, t3 = 0.f;
#pragma unroll
            for (int wv = 0; wv < 4; ++wv) {
                t0 += sred[wv * 4 + 0]; t1 += sred[wv * 4 + 1];
                t2 += sred[wv * 4 + 2]; t3 += sred[wv * 4 + 3];
            }
            atomicAdd(&stats[c * 4 + 0], t0);
            atomicAdd(&stats[c * 4 + 1], t1);
            atomicAdd(&stats[c * 4 + 2], t2);
            atomicAdd(&stats[c * 4 + 3], t3);
        }
    }

    __threadfence();
    cg::this_grid().sync();

    const float inv_cnt = 1.0f / (float)(NB * OH * OW);

#pragma unroll
    for (int p = 0; p < PPB; ++p) {
        const int nc = blockIdx.x + p * GRID;
        const int c  = nc % CH;

        // device-scope coherent stat loads (lanes 0-3), wave broadcast
        float stv = 0.0f;
        if (lane < 4)
            stv = __hip_atomic_load(&stats[c * 4 + lane],
                                    __ATOMIC_RELAXED, __HIP_MEMORY_SCOPE_AGENT);
        const float sum_l = __shfl(stv, 0);
        const float ssq_l = __shfl(stv, 1);
        const float sum_s = __shfl(stv, 2);
        const float ssq_s = __shfl(stv, 3);

        const float mean_l = sum_l * inv_cnt;
        const float var_l  = ssq_l * inv_cnt - mean_l * mean_l;
        const float sc_l   = gamma_lk[c] * rsqrtf(var_l + 1e-5f);
        const float sh_l   = beta_lk[c] - mean_l * sc_l;

        const float mean_s = sum_s * inv_cnt;
        const float var_s  = ssq_s * inv_cnt - mean_s * mean_s;
        const float sc_s   = gamma_sk[c] * rsqrtf(var_s + 1e-5f);
        const float sh_s   = beta_sk[c] - mean_s * sc_s;

        float* op = out + (size_t)nc * (OH * OW);
#pragma unroll
        for (int j = 0; j < 4; ++j) {
            const __half2 h = *reinterpret_cast<const __half2*>(&state[p][j]);
            const float v = fmaf(__low2float(h), sc_l, sh_l)
                          + fmaf(__high2float(h), sc_s, sh_s);
            op[(oyq * 4 + j) * OW + ox] =
                0.5f * v * (1.0f + erff(v * 0.70710678118654752f));
        }
    }
}

// ===========================================================================
// Fallback path (round-4 proven kernels): conv+stats -> finalize -> apply.
// ===========================================================================
__global__ __launch_bounds__(256) void conv_stats_kernel(
    const float* __restrict__ x,
    const float* __restrict__ w_lk,
    const float* __restrict__ w_sk,
    __half2* __restrict__ yls,
    float* __restrict__ stats)
{
    __shared__ float sx2[2][PR][PW];
    __shared__ float sred[4 * 4];

    const int nc = blockIdx.x;
    const int c  = nc % CH;
    const float* xp = x + (size_t)nc * (IH * IW);
    const int tid = threadIdx.x;

    float* sflat = &sx2[0][0][0];
    for (int i = tid; i < 2 * PR * PW; i += 256) sflat[i] = 0.0f;
    __syncthreads();

    const float4* xp4 = (const float4*)xp;
#pragma unroll
    for (int it = 0; it < 4; ++it) {
        const int i = tid + it * 256;
        const float4 v = xp4[i];
        const int r = (i >> 4) + 3;
        const int q = i & 15;
        sx2[1][r][2 * q + 1] = v.x;
        sx2[0][r][2 * q + 2] = v.y;
        sx2[1][r][2 * q + 2] = v.z;
        sx2[0][r][2 * q + 3] = v.w;
    }
    __syncthreads();

    float wl[49], ws9[9];
#pragma unroll
    for (int t = 0; t < 49; ++t) wl[t] = w_lk[c * 49 + t];
#pragma unroll
    for (int t = 0; t < 9; ++t)  ws9[t] = w_sk[c * 9 + t];

    const int ox  = tid & 31;
    const int oyq = tid >> 5;
    const int pr0 = oyq * 8;

    float accl[4] = {0.f, 0.f, 0.f, 0.f};
    float accs[4] = {0.f, 0.f, 0.f, 0.f};

#pragma unroll
    for (int k = 0; k < 13; ++k) {
        const float e0 = sx2[0][pr0 + k][ox];
        const float o0 = sx2[1][pr0 + k][ox];
        const float e1 = sx2[0][pr0 + k][ox + 1];
        const float o1 = sx2[1][pr0 + k][ox + 1];
        const float e2 = sx2[0][pr0 + k][ox + 2];
        const float o2 = sx2[1][pr0 + k][ox + 2];
        const float e3 = sx2[0][pr0 + k][ox + 3];
#pragma unroll
        for (int j = 0; j < 4; ++j) {
            if (k >= 2 * j && k <= 2 * j + 6) {
                const int ky = k - 2 * j;
                accl[j] = fmaf(e0, wl[ky * 7 + 0], accl[j]);
                accl[j] = fmaf(o0, wl[ky * 7 + 1], accl[j]);
                accl[j] = fmaf(e1, wl[ky * 7 + 2], accl[j]);
                accl[j] = fmaf(o1, wl[ky * 7 + 3], accl[j]);
                accl[j] = fmaf(e2, wl[ky * 7 + 4], accl[j]);
                accl[j] = fmaf(o2, wl[ky * 7 + 5], accl[j]);
                accl[j] = fmaf(e3, wl[ky * 7 + 6], accl[j]);
            }
            if (k >= 2 * j + 2 && k <= 2 * j + 4) {
                const int ky = k - 2 * j - 2;
                accs[j] = fmaf(e1, ws9[ky * 3 + 0], accs[j]);
                accs[j] = fmaf(o1, ws9[ky * 3 + 1], accs[j]);
                accs[j] = fmaf(e2, ws9[ky * 3 + 2], accs[j]);
            }
        }
    }

    float s0 = 0.f, s1 = 0.f, s2 = 0.f, s3 = 0.f;
    __half2* yp = yls + (size_t)nc * (OH * OW);
#pragma unroll
    for (int j = 0; j < 4; ++j) {
        const int oy = oyq * 4 + j;
        yp[oy * OW + ox] = __floats2half2_rn(accl[j], accs[j]);
        s0 += accl[j]; s1 += accl[j] * accl[j];
        s2 += accs[j]; s3 += accs[j] * accs[j];
    }

#pragma unroll
    for (int off = 32; off >= 1; off >>= 1) {
        s0 += __shfl_down(s0, off);
        s1 += __shfl_down(s1, off);
        s2 += __shfl_down(s2, off);
        s3 += __shfl_down(s3, off);
    }
    const int wave = tid >> 6;
    if ((tid & 63) == 0) {
        sred[wave * 4 + 0] = s0; sred[wave * 4 + 1] = s1;
        sred[wave * 4 + 2] = s2; sred[wave * 4 + 3] = s3;
    }
    __syncthreads();
    if (tid == 0) {
        float t0 = 0.f, t1 = 0.f, t2 = 0.f, t3 = 0.f;
#pragma unroll
        for (int wv = 0; wv < 4; ++wv) {
            t0 += sred[wv * 4 + 0]; t1 += sred[wv * 4 + 1];
            t2 += sred[wv * 4 + 2]; t3 += sred[wv * 4 + 3];
        }
        atomicAdd(&stats[c * 4 + 0], t0);
        atomicAdd(&stats[c * 4 + 1], t1);
        atomicAdd(&stats[c * 4 + 2], t2);
        atomicAdd(&stats[c * 4 + 3], t3);
    }
}

__global__ void finalize_kernel(
    const float* __restrict__ stats,
    const float* __restrict__ gamma_lk, const float* __restrict__ beta_lk,
    const float* __restrict__ gamma_sk, const float* __restrict__ beta_sk,
    float* __restrict__ params)
{
    const int c = blockIdx.x * blockDim.x + threadIdx.x;
    if (c >= CH) return;
    const float inv_cnt = 1.0f / (float)(NB * OH * OW);

    float mean_l = stats[c * 4 + 0] * inv_cnt;
    float var_l  = stats[c * 4 + 1] * inv_cnt - mean_l * mean_l;
    float sc_l   = gamma_lk[c] * rsqrtf(var_l + 1e-5f);
    float sh_l   = beta_lk[c] - mean_l * sc_l;

    float mean_s = stats[c * 4 + 2] * inv_cnt;
    float var_s  = stats[c * 4 + 3] * inv_cnt - mean_s * mean_s;
    float sc_s   = gamma_sk[c] * rsqrtf(var_s + 1e-5f);
    float sh_s   = beta_sk[c] - mean_s * sc_s;

    params[c * 4 + 0] = sc_l; params[c * 4 + 1] = sh_l;
    params[c * 4 + 2] = sc_s; params[c * 4 + 3] = sh_s;
}

#define N4 (NB * CH * OH * OW / 4)

__global__ __launch_bounds__(256) void apply_kernel(
    const uint4* __restrict__ yls4,
    const float* __restrict__ params,
    float4* __restrict__ out)
{
    int i = blockIdx.x * 256 + threadIdx.x;
    const int stride = gridDim.x * 256;
    for (; i < N4; i += stride) {
        const int c = (i >> 8) % CH;
        const float sc_l = params[c * 4 + 0];
        const float sh_l = params[c * 4 + 1];
        const float sc_s = params[c * 4 + 2];
        const float sh_s = params[c * 4 + 3];

        const uint4 v = yls4[i];
        const __half2 h0 = *reinterpret_cast<const __half2*>(&v.x);
        const __half2 h1 = *reinterpret_cast<const __half2*>(&v.y);
        const __half2 h2 = *reinterpret_cast<const __half2*>(&v.z);
        const __half2 h3 = *reinterpret_cast<const __half2*>(&v.w);

        float v0 = fmaf(__low2float(h0), sc_l, sh_l) + fmaf(__high2float(h0), sc_s, sh_s);
        float v1 = fmaf(__low2float(h1), sc_l, sh_l) + fmaf(__high2float(h1), sc_s, sh_s);
        float v2 = fmaf(__low2float(h2), sc_l, sh_l) + fmaf(__high2float(h2), sc_s, sh_s);
        float v3 = fmaf(__low2float(h3), sc_l, sh_l) + fmaf(__high2float(h3), sc_s, sh_s);

        float4 r;
        r.x = 0.5f * v0 * (1.0f + erff(v0 * 0.70710678118654752f));
        r.y = 0.5f * v1 * (1.0f + erff(v1 * 0.70710678118654752f));
        r.z = 0.5f * v2 * (1.0f + erff(v2 * 0.70710678118654752f));
        r.w = 0.5f * v3 * (1.0f + erff(v3 * 0.70710678118654752f));
        out[i] = r;
    }
}

extern "C" void kernel_launch(void* const* d_in, const int* in_sizes, int n_in,
                              void* d_out, int out_size, void* d_ws, size_t ws_size,
                              hipStream_t stream) {
    const float* x        = (const float*)d_in[0];
    const float* w_lk     = (const float*)d_in[1];
    const float* gamma_lk = (const float*)d_in[2];
    const float* beta_lk  = (const float*)d_in[3];
    const float* w_sk     = (const float*)d_in[4];
    const float* gamma_sk = (const float*)d_in[5];
    const float* beta_sk  = (const float*)d_in[6];
    float* out   = (float*)d_out;
    float* stats = (float*)d_ws;             // CH*4 floats

    hipMemsetAsync(stats, 0, CH * 4 * sizeof(float), stream);

    // ---- capability probing (host-side queries only; deterministic) ----
    int dev = 0;
    hipGetDevice(&dev);
    int coop = 0;
    hipDeviceGetAttribute(&coop, hipDeviceAttributeCooperativeLaunch, dev);
    int numCU = 0;
    hipDeviceGetAttribute(&numCU, hipDeviceAttributeMultiprocessorCount, dev);

    void* args[] = {
        (void*)&x, (void*)&w_lk, (void*)&w_sk,
        (void*)&gamma_lk, (void*)&beta_lk,
        (void*)&gamma_sk, (void*)&beta_sk,
        (void*)&stats, (void*)&out
    };

    bool done = false;
    if (coop && numCU > 0) {
        int nb = 0;
        if (hipOccupancyMaxActiveBlocksPerMultiprocessor(
                &nb, fused_kernel<1024>, 256, 0) == hipSuccess &&
            nb * numCU >= 1024) {
            done = (hipLaunchCooperativeKernel((const void*)fused_kernel<1024>,
                                               dim3(1024), dim3(256), args, 0,
                                               stream) == hipSuccess);
        }
        if (!done) {
            nb = 0;
            if (hipOccupancyMaxActiveBlocksPerMultiprocessor(
                    &nb, fused_kernel<512>, 256, 0) == hipSuccess &&
                nb * numCU >= 512) {
                done = (hipLaunchCooperativeKernel((const void*)fused_kernel<512>,
                                                   dim3(512), dim3(256), args, 0,
                                                   stream) == hipSuccess);
            }
        }
    }

    if (!done) {
        // proven 3-kernel path
        float* params = stats + CH * 4;
        __half2* yls  = (__half2*)(params + CH * 4);
        conv_stats_kernel<<<NB * CH, 256, 0, stream>>>(x, w_lk, w_sk, yls, stats);
        finalize_kernel<<<(CH + 255) / 256, 256, 0, stream>>>(
            stats, gamma_lk, beta_lk, gamma_sk, beta_sk, params);
        apply_kernel<<<4096, 256, 0, stream>>>((const uint4*)yls, params, (float4*)out);
    }
}

// Round 7
// 73.076 us; speedup vs baseline: 1.1046x; 1.1046x over previous
//
#include <hip/hip_runtime.h>
#include <hip/hip_fp16.h>
#include <cmath>

#define NB 32
#define CH 384
#define IH 64
#define IW 64
#define OH 32
#define OW 32
#define PR 70    // padded rows: iy -3..66 -> pr 0..69
#define PWQ 18   // quad-split width: padded col c -> class (c&3), quad (c>>2)

// ---------------------------------------------------------------------------
// Pass 1: 7x7 + 3x3 depthwise conv (stride 2), one 128-thread block per
// (n,c) plane. Quad-split LDS: sxq[class][row][quad], class = padded_col & 3.
// Each thread computes a 4-row x 2-col output tile (8 px): 13 rows x 9 reads
// = 117 LDS reads per 8 outputs. Reads are 2-way bank aliased (free).
// Outputs packed half2{y_lk,y_sk} -> uint2 per col-pair; fp32 channel stats
// via atomics.
// ---------------------------------------------------------------------------
__global__ __launch_bounds__(128, 4) void conv_stats_kernel(
    const float* __restrict__ x,
    const float* __restrict__ w_lk,
    const float* __restrict__ w_sk,
    uint2* __restrict__ yls,     // [planes][OH*OW/2] packed pairs
    float* __restrict__ stats)   // [CH][4] = {sum_l, sumsq_l, sum_s, sumsq_s}
{
    __shared__ float sxq[4][PR][PWQ];
    __shared__ float sred[2 * 4];

    const int nc  = blockIdx.x;
    const int c   = nc % CH;
    const int tid = threadIdx.x;

    // ---- zero halo only (interior fully overwritten by staging) ----
    // top rows 0..2 and bottom rows 67..69, all classes/quads
    for (int i = tid; i < 4 * 3 * PWQ; i += 128) {
        const int f = i / (3 * PWQ);
        const int rem = i % (3 * PWQ);
        const int r = rem / PWQ, q = rem % PWQ;
        sxq[f][r][q] = 0.0f;
        sxq[f][67 + r][q] = 0.0f;
    }
    // side cols (padded cols 0,1,2 and 67,68,69) for rows 3..66
    for (int i = tid; i < 64 * 6; i += 128) {
        const int r = 3 + i / 6;
        const int t = i % 6;
        const int f = (t < 3) ? t : ((t == 3) ? 3 : t - 4);
        const int q = (t < 3) ? 0 : ((t == 3) ? 16 : 17);
        sxq[f][r][q] = 0.0f;
    }

    // ---- stage plane (float4), scatter into quad classes ----
    const float4* xp4 = (const float4*)(x + (size_t)nc * (IH * IW));
#pragma unroll
    for (int it = 0; it < 8; ++it) {
        const int i = tid + it * 128;
        const float4 v = xp4[i];
        const int r  = (i >> 4) + 3;   // 16 float4 per 64-wide row
        const int q4 = i & 15;         // cols 4q4..4q4+3 -> padded 4q4+3..4q4+6
        sxq[3][r][q4]     = v.x;       // cp = 4q4+3: class 3, quad q4
        sxq[0][r][q4 + 1] = v.y;       // cp = 4q4+4: class 0, quad q4+1
        sxq[1][r][q4 + 1] = v.z;       // cp = 4q4+5: class 1, quad q4+1
        sxq[2][r][q4 + 1] = v.w;       // cp = 4q4+6: class 2, quad q4+1
    }
    __syncthreads();

    // per-channel weights (block-uniform -> scalar loads)
    float wl[49], ws9[9];
#pragma unroll
    for (int t = 0; t < 49; ++t) wl[t] = w_lk[c * 49 + t];
#pragma unroll
    for (int t = 0; t < 9; ++t)  ws9[t] = w_sk[c * 9 + t];

    const int lane = tid & 63;
    const int wv   = tid >> 6;        // 0..1
    const int j16  = lane & 15;       // col-pair index; qb = j16
    const int g    = lane >> 4;       // 0..3 row group
    const int qb   = j16;
    const int ox0  = 2 * j16;         // output cols ox0, ox0+1
    const int oy0  = (wv * 4 + g) * 4;// output rows oy0..oy0+3
    const int prb  = 2 * oy0;

    // A = col ox0 (padded base 4qb), B = col ox0+1 (padded base 4qb+2)
    float alA[4] = {0.f,0.f,0.f,0.f}, alB[4] = {0.f,0.f,0.f,0.f};
    float asA[4] = {0.f,0.f,0.f,0.f}, asB[4] = {0.f,0.f,0.f,0.f};

#pragma unroll
    for (int k = 0; k < 13; ++k) {
        const int pr = prb + k;
        const float E0 = sxq[0][pr][qb];       // padded col 4qb
        const float E1 = sxq[0][pr][qb + 1];   // 4qb+4
        const float E2 = sxq[0][pr][qb + 2];   // 4qb+8
        const float F0 = sxq[1][pr][qb];       // 4qb+1
        const float F1 = sxq[1][pr][qb + 1];   // 4qb+5
        const float G0 = sxq[2][pr][qb];       // 4qb+2
        const float G1 = sxq[2][pr][qb + 1];   // 4qb+6
        const float H0 = sxq[3][pr][qb];       // 4qb+3
        const float H1 = sxq[3][pr][qb + 1];   // 4qb+7
#pragma unroll
        for (int j = 0; j < 4; ++j) {
            if (k >= 2 * j && k <= 2 * j + 6) {        // folds at compile time
                const int ky = k - 2 * j;
                alA[j] = fmaf(E0, wl[ky * 7 + 0], alA[j]);
                alA[j] = fmaf(F0, wl[ky * 7 + 1], alA[j]);
                alA[j] = fmaf(G0, wl[ky * 7 + 2], alA[j]);
                alA[j] = fmaf(H0, wl[ky * 7 + 3], alA[j]);
                alA[j] = fmaf(E1, wl[ky * 7 + 4], alA[j]);
                alA[j] = fmaf(F1, wl[ky * 7 + 5], alA[j]);
                alA[j] = fmaf(G1, wl[ky * 7 + 6], alA[j]);
                alB[j] = fmaf(G0, wl[ky * 7 + 0], alB[j]);
                alB[j] = fmaf(H0, wl[ky * 7 + 1], alB[j]);
                alB[j] = fmaf(E1, wl[ky * 7 + 2], alB[j]);
                alB[j] = fmaf(F1, wl[ky * 7 + 3], alB[j]);
                alB[j] = fmaf(G1, wl[ky * 7 + 4], alB[j]);
                alB[j] = fmaf(H1, wl[ky * 7 + 5], alB[j]);
                alB[j] = fmaf(E2, wl[ky * 7 + 6], alB[j]);
            }
            if (k >= 2 * j + 2 && k <= 2 * j + 4) {
                const int kys = k - 2 * j - 2;
                asA[j] = fmaf(G0, ws9[kys * 3 + 0], asA[j]);
                asA[j] = fmaf(H0, ws9[kys * 3 + 1], asA[j]);
                asA[j] = fmaf(E1, ws9[kys * 3 + 2], asA[j]);
                asB[j] = fmaf(E1, ws9[kys * 3 + 0], asB[j]);
                asB[j] = fmaf(F1, ws9[kys * 3 + 1], asB[j]);
                asB[j] = fmaf(G1, ws9[kys * 3 + 2], asB[j]);
            }
        }
    }

    // store packed fp16 pairs, accumulate fp32 stats
    float s0 = 0.f, s1 = 0.f, s2 = 0.f, s3 = 0.f;
    uint2* yp = yls + (size_t)nc * (OH * OW / 2);
#pragma unroll
    for (int j = 0; j < 4; ++j) {
        const int oy = oy0 + j;
        const __half2 hA = __floats2half2_rn(alA[j], asA[j]);
        const __half2 hB = __floats2half2_rn(alB[j], asB[j]);
        uint2 u;
        u.x = *reinterpret_cast<const unsigned int*>(&hA);
        u.y = *reinterpret_cast<const unsigned int*>(&hB);
        yp[oy * (OW / 2) + j16] = u;
        s0 += alA[j] + alB[j];
        s1 += alA[j] * alA[j] + alB[j] * alB[j];
        s2 += asA[j] + asB[j];
        s3 += asA[j] * asA[j] + asB[j] * asB[j];
    }

#pragma unroll
    for (int off = 32; off >= 1; off >>= 1) {
        s0 += __shfl_down(s0, off);
        s1 += __shfl_down(s1, off);
        s2 += __shfl_down(s2, off);
        s3 += __shfl_down(s3, off);
    }
    if (lane == 0) {
        sred[wv * 4 + 0] = s0; sred[wv * 4 + 1] = s1;
        sred[wv * 4 + 2] = s2; sred[wv * 4 + 3] = s3;
    }
    __syncthreads();
    if (tid == 0) {
        atomicAdd(&stats[c * 4 + 0], sred[0] + sred[4]);
        atomicAdd(&stats[c * 4 + 1], sred[1] + sred[5]);
        atomicAdd(&stats[c * 4 + 2], sred[2] + sred[6]);
        atomicAdd(&stats[c * 4 + 3], sred[3] + sred[7]);
    }
}

// ---------------------------------------------------------------------------
// Pass 2: one block per (n,c) plane (256 threads = 256 uint4 = 1024 px).
// Channel is block-uniform -> fold BN from stats inline (no finalize kernel).
// Unpack 4 half2 pixels / uint4, affine both branches, add, exact GELU.
// ---------------------------------------------------------------------------
__global__ __launch_bounds__(256) void apply_kernel(
    const uint4* __restrict__ yls4,
    const float* __restrict__ stats,
    const float* __restrict__ gamma_lk, const float* __restrict__ beta_lk,
    const float* __restrict__ gamma_sk, const float* __restrict__ beta_sk,
    float4* __restrict__ out)
{
    const int b = blockIdx.x;
    const int c = b % CH;
    const float inv_cnt = 1.0f / (float)(NB * OH * OW);

    const float mean_l = stats[c * 4 + 0] * inv_cnt;
    const float var_l  = stats[c * 4 + 1] * inv_cnt - mean_l * mean_l;
    const float sc_l   = gamma_lk[c] * rsqrtf(var_l + 1e-5f);
    const float sh_l   = beta_lk[c] - mean_l * sc_l;

    const float mean_s = stats[c * 4 + 2] * inv_cnt;
    const float var_s  = stats[c * 4 + 3] * inv_cnt - mean_s * mean_s;
    const float sc_s   = gamma_sk[c] * rsqrtf(var_s + 1e-5f);
    const float sh_s   = beta_sk[c] - mean_s * sc_s;

    const int i = b * 256 + threadIdx.x;
    const uint4 v = yls4[i];
    const __half2 h0 = *reinterpret_cast<const __half2*>(&v.x);
    const __half2 h1 = *reinterpret_cast<const __half2*>(&v.y);
    const __half2 h2 = *reinterpret_cast<const __half2*>(&v.z);
    const __half2 h3 = *reinterpret_cast<const __half2*>(&v.w);

    const float v0 = fmaf(__low2float(h0), sc_l, sh_l) + fmaf(__high2float(h0), sc_s, sh_s);
    const float v1 = fmaf(__low2float(h1), sc_l, sh_l) + fmaf(__high2float(h1), sc_s, sh_s);
    const float v2 = fmaf(__low2float(h2), sc_l, sh_l) + fmaf(__high2float(h2), sc_s, sh_s);
    const float v3 = fmaf(__low2float(h3), sc_l, sh_l) + fmaf(__high2float(h3), sc_s, sh_s);

    float4 r;
    r.x = 0.5f * v0 * (1.0f + erff(v0 * 0.70710678118654752f));
    r.y = 0.5f * v1 * (1.0f + erff(v1 * 0.70710678118654752f));
    r.z = 0.5f * v2 * (1.0f + erff(v2 * 0.70710678118654752f));
    r.w = 0.5f * v3 * (1.0f + erff(v3 * 0.70710678118654752f));
    out[i] = r;
}

extern "C" void kernel_launch(void* const* d_in, const int* in_sizes, int n_in,
                              void* d_out, int out_size, void* d_ws, size_t ws_size,
                              hipStream_t stream) {
    const float* x        = (const float*)d_in[0];
    const float* w_lk     = (const float*)d_in[1];
    const float* gamma_lk = (const float*)d_in[2];
    const float* beta_lk  = (const float*)d_in[3];
    const float* w_sk     = (const float*)d_in[4];
    const float* gamma_sk = (const float*)d_in[5];
    const float* beta_sk  = (const float*)d_in[6];
    float* out   = (float*)d_out;

    float* stats = (float*)d_ws;                 // CH*4 floats (6 KB)
    uint2* yls   = (uint2*)(stats + CH * 4);     // 50 MB packed fp16 pairs

    hipMemsetAsync(stats, 0, CH * 4 * sizeof(float), stream);

    conv_stats_kernel<<<NB * CH, 128, 0, stream>>>(x, w_lk, w_sk, yls, stats);
    apply_kernel<<<NB * CH, 256, 0, stream>>>(
        (const uint4*)yls, stats, gamma_lk, beta_lk, gamma_sk, beta_sk,
        (float4*)out);
}

// Round 8
// 69.138 us; speedup vs baseline: 1.1676x; 1.0570x over previous
//
#include <hip/hip_runtime.h>
#include <hip/hip_fp16.h>
#include <cmath>

#define NB 32
#define CH 384
#define IH 64
#define IW 64
#define OH 32
#define OW 32
#define PR 70    // padded rows: iy -3..66 -> pr 0..69
#define PWQ 18   // quad-split width: padded col c -> class (c&3), quad (c>>2)

// ---------------------------------------------------------------------------
// Pass 1: 7x7 + 3x3 depthwise conv (stride 2), one 128-thread block per
// (n,c) plane. Quad-split LDS: sxq[class][row][quad], class = padded_col & 3.
// Each thread computes a 4-row x 2-col output tile (8 px): 13 rows x 9 b32
// reads per 8 outputs, 2-way bank aliased (free).
// Outputs packed half2{y_lk,y_sk}; per-wave stats written NON-atomically to
// a partials slab (every slot written every call -> no memset needed).
// ---------------------------------------------------------------------------
__global__ __launch_bounds__(128, 4) void conv_stats_kernel(
    const float* __restrict__ x,
    const float* __restrict__ w_lk,
    const float* __restrict__ w_sk,
    uint2* __restrict__ yls,        // [planes][OH*OW/2] packed pairs
    float* __restrict__ partial)    // [CH][NB][2][4] per-wave partial sums
{
    __shared__ float sxq[4][PR][PWQ];

    const int nc  = blockIdx.x;
    const int n   = nc / CH;
    const int c   = nc % CH;
    const int tid = threadIdx.x;

    // ---- zero halo only (interior fully overwritten by staging) ----
    for (int i = tid; i < 4 * 3 * PWQ; i += 128) {
        const int f = i / (3 * PWQ);
        const int rem = i % (3 * PWQ);
        const int r = rem / PWQ, q = rem % PWQ;
        sxq[f][r][q] = 0.0f;
        sxq[f][67 + r][q] = 0.0f;
    }
    for (int i = tid; i < 64 * 6; i += 128) {
        const int r = 3 + i / 6;
        const int t = i % 6;
        const int f = (t < 3) ? t : ((t == 3) ? 3 : t - 4);
        const int q = (t < 3) ? 0 : ((t == 3) ? 16 : 17);
        sxq[f][r][q] = 0.0f;
    }

    // ---- stage plane (float4), scatter into quad classes ----
    const float4* xp4 = (const float4*)(x + (size_t)nc * (IH * IW));
#pragma unroll
    for (int it = 0; it < 8; ++it) {
        const int i = tid + it * 128;
        const float4 v = xp4[i];
        const int r  = (i >> 4) + 3;   // 16 float4 per 64-wide row
        const int q4 = i & 15;         // cols 4q4..4q4+3 -> padded 4q4+3..4q4+6
        sxq[3][r][q4]     = v.x;       // cp = 4q4+3: class 3, quad q4
        sxq[0][r][q4 + 1] = v.y;       // cp = 4q4+4: class 0, quad q4+1
        sxq[1][r][q4 + 1] = v.z;       // cp = 4q4+5: class 1, quad q4+1
        sxq[2][r][q4 + 1] = v.w;       // cp = 4q4+6: class 2, quad q4+1
    }
    __syncthreads();

    // per-channel weights (block-uniform -> scalar loads)
    float wl[49], ws9[9];
#pragma unroll
    for (int t = 0; t < 49; ++t) wl[t] = w_lk[c * 49 + t];
#pragma unroll
    for (int t = 0; t < 9; ++t)  ws9[t] = w_sk[c * 9 + t];

    const int lane = tid & 63;
    const int wv   = tid >> 6;        // 0..1
    const int j16  = lane & 15;       // col-pair index; qb = j16
    const int g    = lane >> 4;       // 0..3 row group
    const int qb   = j16;
    const int oy0  = (wv * 4 + g) * 4;// output rows oy0..oy0+3
    const int prb  = 2 * oy0;

    // A = col 2*j16 (padded base 4qb), B = col 2*j16+1 (padded base 4qb+2)
    float alA[4] = {0.f,0.f,0.f,0.f}, alB[4] = {0.f,0.f,0.f,0.f};
    float asA[4] = {0.f,0.f,0.f,0.f}, asB[4] = {0.f,0.f,0.f,0.f};

#pragma unroll
    for (int k = 0; k < 13; ++k) {
        const int pr = prb + k;
        const float E0 = sxq[0][pr][qb];       // padded col 4qb
        const float E1 = sxq[0][pr][qb + 1];   // 4qb+4
        const float E2 = sxq[0][pr][qb + 2];   // 4qb+8
        const float F0 = sxq[1][pr][qb];       // 4qb+1
        const float F1 = sxq[1][pr][qb + 1];   // 4qb+5
        const float G0 = sxq[2][pr][qb];       // 4qb+2
        const float G1 = sxq[2][pr][qb + 1];   // 4qb+6
        const float H0 = sxq[3][pr][qb];       // 4qb+3
        const float H1 = sxq[3][pr][qb + 1];   // 4qb+7
#pragma unroll
        for (int j = 0; j < 4; ++j) {
            if (k >= 2 * j && k <= 2 * j + 6) {        // folds at compile time
                const int ky = k - 2 * j;
                alA[j] = fmaf(E0, wl[ky * 7 + 0], alA[j]);
                alA[j] = fmaf(F0, wl[ky * 7 + 1], alA[j]);
                alA[j] = fmaf(G0, wl[ky * 7 + 2], alA[j]);
                alA[j] = fmaf(H0, wl[ky * 7 + 3], alA[j]);
                alA[j] = fmaf(E1, wl[ky * 7 + 4], alA[j]);
                alA[j] = fmaf(F1, wl[ky * 7 + 5], alA[j]);
                alA[j] = fmaf(G1, wl[ky * 7 + 6], alA[j]);
                alB[j] = fmaf(G0, wl[ky * 7 + 0], alB[j]);
                alB[j] = fmaf(H0, wl[ky * 7 + 1], alB[j]);
                alB[j] = fmaf(E1, wl[ky * 7 + 2], alB[j]);
                alB[j] = fmaf(F1, wl[ky * 7 + 3], alB[j]);
                alB[j] = fmaf(G1, wl[ky * 7 + 4], alB[j]);
                alB[j] = fmaf(H1, wl[ky * 7 + 5], alB[j]);
                alB[j] = fmaf(E2, wl[ky * 7 + 6], alB[j]);
            }
            if (k >= 2 * j + 2 && k <= 2 * j + 4) {
                const int kys = k - 2 * j - 2;
                asA[j] = fmaf(G0, ws9[kys * 3 + 0], asA[j]);
                asA[j] = fmaf(H0, ws9[kys * 3 + 1], asA[j]);
                asA[j] = fmaf(E1, ws9[kys * 3 + 2], asA[j]);
                asB[j] = fmaf(E1, ws9[kys * 3 + 0], asB[j]);
                asB[j] = fmaf(F1, ws9[kys * 3 + 1], asB[j]);
                asB[j] = fmaf(G1, ws9[kys * 3 + 2], asB[j]);
            }
        }
    }

    // store packed fp16 pairs, accumulate per-thread stats
    float s0 = 0.f, s1 = 0.f, s2 = 0.f, s3 = 0.f;
    uint2* yp = yls + (size_t)nc * (OH * OW / 2);
#pragma unroll
    for (int j = 0; j < 4; ++j) {
        const int oy = oy0 + j;
        const __half2 hA = __floats2half2_rn(alA[j], asA[j]);
        const __half2 hB = __floats2half2_rn(alB[j], asB[j]);
        uint2 u;
        u.x = *reinterpret_cast<const unsigned int*>(&hA);
        u.y = *reinterpret_cast<const unsigned int*>(&hB);
        yp[oy * (OW / 2) + j16] = u;
        s0 += alA[j] + alB[j];
        s1 += alA[j] * alA[j] + alB[j] * alB[j];
        s2 += asA[j] + asB[j];
        s3 += asA[j] * asA[j] + asB[j] * asB[j];
    }

    // wave64 butterfly reduce, lane 0 writes this wave's partial (no atomics)
#pragma unroll
    for (int off = 32; off >= 1; off >>= 1) {
        s0 += __shfl_down(s0, off);
        s1 += __shfl_down(s1, off);
        s2 += __shfl_down(s2, off);
        s3 += __shfl_down(s3, off);
    }
    if (lane == 0) {
        float4 w4 = make_float4(s0, s1, s2, s3);
        ((float4*)partial)[(c * NB + n) * 2 + wv] = w4;
    }
}

// ---------------------------------------------------------------------------
// Pass 2: one block per (n,c) plane (256 threads = 256 uint4 = 1024 px).
// Wave 0 reduces this channel's 256 partial floats (64 lanes x float4) via
// butterfly shuffles, lane 0 folds BN -> 4 params in LDS; then all threads
// unpack 4 half2 px/uint4, affine both branches, add, exact GELU.
// ---------------------------------------------------------------------------
__global__ __launch_bounds__(256) void apply_kernel(
    const uint4* __restrict__ yls4,
    const float* __restrict__ partial,
    const float* __restrict__ gamma_lk, const float* __restrict__ beta_lk,
    const float* __restrict__ gamma_sk, const float* __restrict__ beta_sk,
    float4* __restrict__ out)
{
    __shared__ float sp[4];

    const int b = blockIdx.x;
    const int c = b % CH;
    const int tid = threadIdx.x;

    if (tid < 64) {
        // lane l reads partial[c*256 + 4l .. +3] = one wave-partial float4
        float4 v = ((const float4*)partial)[c * 64 + tid];
        float s0 = v.x, s1 = v.y, s2 = v.z, s3 = v.w;
#pragma unroll
        for (int off = 32; off >= 1; off >>= 1) {
            s0 += __shfl_down(s0, off);
            s1 += __shfl_down(s1, off);
            s2 += __shfl_down(s2, off);
            s3 += __shfl_down(s3, off);
        }
        if (tid == 0) {
            const float inv_cnt = 1.0f / (float)(NB * OH * OW);
            const float mean_l = s0 * inv_cnt;
            const float var_l  = s1 * inv_cnt - mean_l * mean_l;
            const float sc_l   = gamma_lk[c] * rsqrtf(var_l + 1e-5f);
            const float sh_l   = beta_lk[c] - mean_l * sc_l;
            const float mean_s = s2 * inv_cnt;
            const float var_s  = s3 * inv_cnt - mean_s * mean_s;
            const float sc_s   = gamma_sk[c] * rsqrtf(var_s + 1e-5f);
            const float sh_s   = beta_sk[c] - mean_s * sc_s;
            sp[0] = sc_l; sp[1] = sh_l; sp[2] = sc_s; sp[3] = sh_s;
        }
    }
    __syncthreads();

    const float sc_l = sp[0], sh_l = sp[1], sc_s = sp[2], sh_s = sp[3];

    const int i = b * 256 + tid;
    const uint4 v = yls4[i];
    const __half2 h0 = *reinterpret_cast<const __half2*>(&v.x);
    const __half2 h1 = *reinterpret_cast<const __half2*>(&v.y);
    const __half2 h2 = *reinterpret_cast<const __half2*>(&v.z);
    const __half2 h3 = *reinterpret_cast<const __half2*>(&v.w);

    const float v0 = fmaf(__low2float(h0), sc_l, sh_l) + fmaf(__high2float(h0), sc_s, sh_s);
    const float v1 = fmaf(__low2float(h1), sc_l, sh_l) + fmaf(__high2float(h1), sc_s, sh_s);
    const float v2 = fmaf(__low2float(h2), sc_l, sh_l) + fmaf(__high2float(h2), sc_s, sh_s);
    const float v3 = fmaf(__low2float(h3), sc_l, sh_l) + fmaf(__high2float(h3), sc_s, sh_s);

    float4 r;
    r.x = 0.5f * v0 * (1.0f + erff(v0 * 0.70710678118654752f));
    r.y = 0.5f * v1 * (1.0f + erff(v1 * 0.70710678118654752f));
    r.z = 0.5f * v2 * (1.0f + erff(v2 * 0.70710678118654752f));
    r.w = 0.5f * v3 * (1.0f + erff(v3 * 0.70710678118654752f));
    out[i] = r;
}

extern "C" void kernel_launch(void* const* d_in, const int* in_sizes, int n_in,
                              void* d_out, int out_size, void* d_ws, size_t ws_size,
                              hipStream_t stream) {
    const float* x        = (const float*)d_in[0];
    const float* w_lk     = (const float*)d_in[1];
    const float* gamma_lk = (const float*)d_in[2];
    const float* beta_lk  = (const float*)d_in[3];
    const float* w_sk     = (const float*)d_in[4];
    const float* gamma_sk = (const float*)d_in[5];
    const float* beta_sk  = (const float*)d_in[6];
    float* out = (float*)d_out;

    float* partial = (float*)d_ws;                       // CH*NB*2*4 floats (393 KB)
    uint2* yls     = (uint2*)(partial + CH * NB * 2 * 4);// 50 MB packed fp16 pairs

    conv_stats_kernel<<<NB * CH, 128, 0, stream>>>(x, w_lk, w_sk, yls, partial);
    apply_kernel<<<NB * CH, 256, 0, stream>>>(
        (const uint4*)yls, partial, gamma_lk, beta_lk, gamma_sk, beta_sk,
        (float4*)out);
}